// Round 19
// baseline (163.852 us; speedup 1.0000x reference)
//
#include <hip/hip_runtime.h>
#include <hip/hip_bf16.h>

// B=2, S=2048, D=1024, H=16, DH=64. f32 in/out; bf16 intermediates for MFMA.
#define Bn 2
#define Sn 2048
#define Dn 1024
#define Hn 16
#define DHn 64
#define Kd 1024
#define Mn (Bn * Sn)
#define LN10K 9.210340371976184f

typedef __attribute__((ext_vector_type(8))) short bf16x8;   // MFMA A/B frag
typedef __attribute__((ext_vector_type(4))) float f32x4;    // 16x16 C/D frag
typedef __attribute__((ext_vector_type(16))) float f32x16;  // 32x32 C/D frag

static __device__ __forceinline__ ushort f2bf(float f) {
    uint u = __float_as_uint(f);
    u += 0x7fff + ((u >> 16) & 1);   // round-nearest-even
    return (ushort)(u >> 16);
}
// packed f32x2 -> bf16x2 (RNE), lo = a, hi = b
static __device__ __forceinline__ uint cvtpk(float a, float b) {
    uint r;
    asm("v_cvt_pk_bf16_f32 %0, %1, %2" : "=v"(r) : "v"(a), "v"(b));
    return r;
}
// swap a.hi32lanes <-> b.lo32lanes
static __device__ __forceinline__ void plswap(uint& a, uint& b) {
    asm volatile("v_permlane32_swap_b32 %0, %1" : "+v"(a), "+v"(b));
}

#define MFMA16(a, b, c) __builtin_amdgcn_mfma_f32_16x16x32_bf16((a), (b), (c), 0, 0, 0)
#define MFMA32(a, b, c) __builtin_amdgcn_mfma_f32_32x32x16_bf16((a), (b), (c), 0, 0, 0)

// async global->LDS, 16B per lane. LDS dest is wave-uniform base + lane*16.
static __device__ __forceinline__ void gload16(const ushort* g, ushort* l) {
    __builtin_amdgcn_global_load_lds(
        (const __attribute__((address_space(1))) void*)g,
        (__attribute__((address_space(3))) void*)l, 16, 0, 0);
}

// XOR swizzle for [rows][128B] LDS tiles (16B granules).
static __device__ __forceinline__ int swz(int row, int col16) {
    return row * 128 + (((col16) * 16) ^ ((row & 7) << 4));
}
// XOR swizzle for [rows][256B] LDS tiles (16 granules/row).
static __device__ __forceinline__ int swzV(int row, int col16) {
    return row * 256 + (((col16) * 16) ^ ((row & 7) << 4));
}

// ---------------------------------------------------------------------------
// Fused prep: [0,2048) cvt x_qk; [2048,4096) cvt x_v; [4096,6144) transpose
// W_qk; [6144,7168) transpose W_v; [7168,7424) RoPE table.
// ---------------------------------------------------------------------------
__global__ __launch_bounds__(256) void prep(
    const float* __restrict__ x_qk, const float* __restrict__ x_v,
    const float* __restrict__ W_qk, const float* __restrict__ W_v,
    ushort* __restrict__ xqkB, ushort* __restrict__ xvB,
    ushort* __restrict__ WqkT, ushort* __restrict__ WvT,
    float* __restrict__ ct, float* __restrict__ st)
{
    __shared__ ushort tle[32][33];
    const int blk = blockIdx.x;
    const int tid = threadIdx.x;

    if (blk < 4096) {
        const float* in = (blk < 2048) ? x_qk : x_v;
        ushort* out = (blk < 2048) ? xqkB : xvB;
        const int lb = (blk < 2048) ? blk : blk - 2048;
        const size_t i = ((size_t)lb * 256 + tid) * 8;
        const float4 a = *(const float4*)(in + i);
        const float4 b = *(const float4*)(in + i + 4);
        *(ushort4*)(out + i) =
            make_ushort4(f2bf(a.x), f2bf(a.y), f2bf(a.z), f2bf(a.w));
        *(ushort4*)(out + i + 4) =
            make_ushort4(f2bf(b.x), f2bf(b.y), f2bf(b.z), f2bf(b.w));
    } else if (blk < 7168) {
        const bool isQK = blk < 6144;
        const int t = isQK ? blk - 4096 : blk - 6144;
        const int C = isQK ? 2048 : 1024;
        const float* in = isQK ? W_qk : W_v;
        ushort* out = isQK ? WqkT : WvT;
        const int n0 = (isQK ? (t & 63) : (t & 31)) * 32;
        const int k0 = (isQK ? (t >> 6) : (t >> 5)) * 32;
        const int x = tid & 31, y = tid >> 5;
#pragma unroll
        for (int i = 0; i < 4; ++i)
            tle[y + 8 * i][x] = f2bf(in[(size_t)(k0 + y + 8 * i) * C + n0 + x]);
        __syncthreads();
#pragma unroll
        for (int i = 0; i < 4; ++i)
            out[(size_t)(n0 + y + 8 * i) * Kd + k0 + x] = tle[x][y + 8 * i];
    } else {
        const int idx = (blk - 7168) * 256 + tid;
        const int s = idx >> 5, fe = idx & 31;
        const float f = expf(-LN10K * (float)fe / 32.0f);
        const float a = (float)s * f;
        ct[idx] = cosf(a);
        st[idx] = sinf(a);
    }
}

// ---------------------------------------------------------------------------
// Combined MFMA GEMM (m97-style): blocks x<16 QK-projection (RoPE epilogue
// -> Q,K); x>=16 V-projection (-> V^T). 128x128 tile, BK=64, global_load_lds
// w=16 with xor-source, swizzled read.
// ---------------------------------------------------------------------------
__global__ __launch_bounds__(256) void gemm_fused_all(
    const ushort* __restrict__ xqkB, const ushort* __restrict__ xvB,
    const ushort* __restrict__ WqkT, const ushort* __restrict__ WvT,
    const float* __restrict__ b_qk, const float* __restrict__ b_v,
    const float* __restrict__ ctab, const float* __restrict__ stab,
    ushort* __restrict__ Qw, ushort* __restrict__ Kw, ushort* __restrict__ Vtw)
{
    __shared__ ushort Asm[128 * 64];
    __shared__ ushort Bsm[128 * 64];

    const bool isQK = blockIdx.x < 16;
    const ushort* A  = isQK ? xqkB : xvB;
    const ushort* Bt = isQK ? WqkT : WvT;
    const float* bias = isQK ? b_qk : b_v;
    const int nbase = (isQK ? blockIdx.x : blockIdx.x - 16) * 128;
    const int mbase = blockIdx.y * 128;

    const int tid = threadIdx.x;
    const int lane = tid & 63, w = tid >> 6;
    const int g = lane >> 4, c = lane & 15;
    const int wm = (w >> 1) * 64, wn = (w & 1) * 64;

    f32x4 acc[4][4];
#pragma unroll
    for (int mf = 0; mf < 4; ++mf)
#pragma unroll
        for (int nf = 0; nf < 4; ++nf)
            acc[mf][nf] = (f32x4){0.f, 0.f, 0.f, 0.f};

    const int sbase = w * 64 + lane;

    for (int k0 = 0; k0 < Kd; k0 += 64) {
#pragma unroll
        for (int j = 0; j < 4; ++j) {
            const int i = j * 256 + sbase;
            const int row = i >> 3, c16 = i & 7;
            const int kc = (c16 ^ (row & 7)) * 8;
            gload16(A + (size_t)(mbase + row) * Kd + k0 + kc,
                    &Asm[(size_t)(j * 256 + w * 64) * 8]);
            gload16(Bt + (size_t)(nbase + row) * Kd + k0 + kc,
                    &Bsm[(size_t)(j * 256 + w * 64) * 8]);
        }
        __syncthreads();

#pragma unroll
        for (int ks = 0; ks < 2; ++ks) {
            bf16x8 af[4], bfr[4];
#pragma unroll
            for (int mf = 0; mf < 4; ++mf) {
                const int row = wm + mf * 16 + c;
                af[mf] = *(const bf16x8*)((const char*)Asm + swz(row, ks * 4 + g));
            }
#pragma unroll
            for (int nf = 0; nf < 4; ++nf) {
                const int row = wn + nf * 16 + c;
                bfr[nf] = *(const bf16x8*)((const char*)Bsm + swz(row, ks * 4 + g));
            }
#pragma unroll
            for (int mf = 0; mf < 4; ++mf)
#pragma unroll
                for (int nf = 0; nf < 4; ++nf)
                    acc[mf][nf] = MFMA16(af[mf], bfr[nf], acc[mf][nf]);
        }
        __syncthreads();
    }

#pragma unroll
    for (int nf = 0; nf < 4; ++nf) {
        const int col = nbase + wn + nf * 16 + c;
        const float bs = bias[col];
        if (isQK) {
            const int dh = col & 63, h = (col >> 6) & 15, isK = col >> 10;
            ushort* dst = isK ? Kw : Qw;
            // Q: fold 1/sqrt(64) * log2(e) so attention exps are exp2
            const float sc = isK ? 1.0f : 0.18033688011112042f;
            const float* cr = ctab + (dh & 31);
            const float* sr = stab + (dh & 31);
#pragma unroll
            for (int mf = 0; mf < 4; ++mf) {
#pragma unroll
                for (int r = 0; r < 4; ++r) {
                    const int row = mbase + wm + mf * 16 + g * 4 + r;
                    const int s = row & 2047, b = row >> 11;
                    const float v = acc[mf][nf][r] + bs;
                    const float p = __shfl_xor(v, 1);
                    const float cs = cr[s * 32], sn = sr[s * 32];
                    const float ov = (c & 1) ? v * cs + p * sn
                                             : v * cs - p * sn;
                    dst[(((size_t)(b * Hn + h)) * Sn + s) * DHn + dh] =
                        f2bf(ov * sc);
                }
            }
        } else {
            const int h = col >> 6, dh = col & 63;
#pragma unroll
            for (int mf = 0; mf < 4; ++mf) {
#pragma unroll
                for (int r = 0; r < 4; ++r) {
                    const int row = mbase + wm + mf * 16 + g * 4 + r;
                    const int s = row & 2047, b = row >> 11;
                    const float v = acc[mf][nf][r] + bs;
                    Vtw[(((size_t)(b * Hn + h)) * DHn + dh) * Sn + s] = f2bf(v);
                }
            }
        }
    }
}

// ---------------------------------------------------------------------------
// MFMA flash attention, round 19: KVBLK=128 (16 iters, half the barrier/
// convergence points of r15's 32). Double-buffered LDS (2 x 32KB); per-iter
// sync = vmcnt(0) + raw barrier; stage(t+1) issued right after the barrier
// so its loads overlap the full (2x longer) compute phase (T3-minimum).
// Core math identical to r11/r15: swapped QK^T, in-reg softmax, permlane
// P-rebuild, exp2 domain, defer-max.
// ---------------------------------------------------------------------------
__global__ __launch_bounds__(256) void attn_mfma(
    const ushort* __restrict__ Qg, const ushort* __restrict__ Kg,
    const ushort* __restrict__ Vtg, float* __restrict__ Aw)
{
    __shared__ char Kt[2][16384];   // [128 kv][64 d] bf16, swizzled 128B rows
    __shared__ char Vt[2][16384];   // [64 dh][128 kv] bf16, swizzled 256B rows

    const int tid = threadIdx.x;
    const int lane = tid & 63, w = tid >> 6;
    const int r31 = lane & 31, hi = lane >> 5;
    const int bh = blockIdx.y;
    const int b = bh >> 4, h = bh & 15;
    const int q0 = blockIdx.x * 128 + w * 32;

    // Q B-frags: lane holds Q[q0 + r31][kt*16 + hi*8 + j]
    const ushort* qp = Qg + ((size_t)bh * Sn + q0 + r31) * DHn + hi * 8;
    bf16x8 qf[4];
#pragma unroll
    for (int kt = 0; kt < 4; ++kt)
        qf[kt] = *(const bf16x8*)(qp + kt * 16);

    const ushort* Kb = Kg + (size_t)bh * Sn * DHn;
    const ushort* Vb = Vtg + (size_t)bh * DHn * Sn;

    // stage one 128x64 K tile + one 64x128 V^T tile: 8 gload16 per thread.
    auto stage = [&](int buf, int kb) {
#pragma unroll
        for (int j = 0; j < 4; ++j) {
            const int i = j * 256 + w * 64 + lane;
            // K: 128 rows x 8 granules, xor-source for swz() read
            const int krow = i >> 3, kc16 = i & 7;
            gload16(Kb + (size_t)(kb + krow) * DHn + ((kc16 ^ (krow & 7)) * 8),
                    (ushort*)&Kt[buf][(j * 256 + w * 64) * 16]);
            // V: 64 rows x 16 granules, xor-source for swzV() read
            const int vrow = i >> 4, vc16 = i & 15;
            gload16(Vb + (size_t)vrow * Sn + kb + ((vc16 ^ (vrow & 7)) * 8),
                    (ushort*)&Vt[buf][(j * 256 + w * 64) * 16]);
        }
    };

    stage(0, 0);

    f32x16 acc0, acc1;
#pragma unroll
    for (int i = 0; i < 16; ++i) { acc0[i] = 0.f; acc1[i] = 0.f; }
    float m = -1e30f, lp = 0.f;

    const int NT = Sn / 128;   // 16
    for (int t = 0; t < NT; ++t) {
        const int cur = t & 1;

        // tile t's 8 DMAs were issued a full compute phase ago -> short wait
        asm volatile("s_waitcnt vmcnt(0)" ::: "memory");
        __builtin_amdgcn_sched_barrier(0);
        __builtin_amdgcn_s_barrier();   // all waves done reading buf[cur^1]
        __builtin_amdgcn_sched_barrier(0);
        if (t + 1 < NT) stage(cur ^ 1, (t + 1) * 128);
        __builtin_amdgcn_sched_barrier(0);

        // ---- QK^T swapped: C[kv][q] for four 32-kv tiles ----
        f32x16 C0, C1, C2, C3;
#pragma unroll
        for (int i = 0; i < 16; ++i) { C0[i] = 0.f; C1[i] = 0.f; C2[i] = 0.f; C3[i] = 0.f; }
#pragma unroll
        for (int kt = 0; kt < 4; ++kt) {
            const bf16x8 ka = *(const bf16x8*)&Kt[cur][swz(r31, kt * 2 + hi)];
            C0 = MFMA32(ka, qf[kt], C0);
        }
#pragma unroll
        for (int kt = 0; kt < 4; ++kt) {
            const bf16x8 ka = *(const bf16x8*)&Kt[cur][swz(32 + r31, kt * 2 + hi)];
            C1 = MFMA32(ka, qf[kt], C1);
        }
#pragma unroll
        for (int kt = 0; kt < 4; ++kt) {
            const bf16x8 ka = *(const bf16x8*)&Kt[cur][swz(64 + r31, kt * 2 + hi)];
            C2 = MFMA32(ka, qf[kt], C2);
        }
#pragma unroll
        for (int kt = 0; kt < 4; ++kt) {
            const bf16x8 ka = *(const bf16x8*)&Kt[cur][swz(96 + r31, kt * 2 + hi)];
            C3 = MFMA32(ka, qf[kt], C3);
        }

        // ---- row max over 128 kv (q = r31) ----
        float mx[8];
#pragma unroll
        for (int i = 0; i < 8; ++i) {
            float a01 = fmaxf(fmaxf(C0[i], C0[i + 8]), fmaxf(C1[i], C1[i + 8]));
            float a23 = fmaxf(fmaxf(C2[i], C2[i + 8]), fmaxf(C3[i], C3[i + 8]));
            mx[i] = fmaxf(a01, a23);
        }
        mx[0] = fmaxf(mx[0], mx[4]); mx[1] = fmaxf(mx[1], mx[5]);
        mx[2] = fmaxf(mx[2], mx[6]); mx[3] = fmaxf(mx[3], mx[7]);
        float pmax = fmaxf(fmaxf(mx[0], mx[1]), fmaxf(mx[2], mx[3]));
        pmax = fmaxf(pmax, __shfl_xor(pmax, 32));

        // ---- defer-max rescale (rare; threshold 8*log2e) ----
        if (__any(pmax > m + 11.5f)) {
            const float mn = fmaxf(m, pmax);
            const float a = exp2f(m - mn);
            m = mn;
            lp *= a;
#pragma unroll
            for (int reg = 0; reg < 16; ++reg) {
                const int qr = (reg & 3) + 8 * (reg >> 2) + 4 * hi;
                const float ar = __shfl(a, qr);
                acc0[reg] *= ar;
                acc1[reg] *= ar;
            }
        }

        // ---- exp2 + pack + permlane -> 8 PV A-frags (kv 0..127) ----
        bf16x8 paf[8];
        {
            const f32x16* Cs[4] = {&C0, &C1, &C2, &C3};
#pragma unroll
            for (int tile = 0; tile < 4; ++tile) {
                const f32x16& C = *Cs[tile];
                float e[16];
#pragma unroll
                for (int i = 0; i < 16; ++i) e[i] = exp2f(C[i] - m);
                float s = 0.f;
#pragma unroll
                for (int i = 0; i < 16; ++i) s += e[i];
                lp += s;
                uint p01 = cvtpk(e[0], e[1]),  p23 = cvtpk(e[2], e[3]);
                uint p45 = cvtpk(e[4], e[5]),  p67 = cvtpk(e[6], e[7]);
                uint p89 = cvtpk(e[8], e[9]),  pab = cvtpk(e[10], e[11]);
                uint pcd = cvtpk(e[12], e[13]), pef = cvtpk(e[14], e[15]);
                plswap(p01, p45); plswap(p23, p67);   // kv tile*32 + 0..15
                plswap(p89, pcd); plswap(pab, pef);   // kv tile*32 + 16..31
                uint4 f0 = {p01, p23, p45, p67};
                uint4 f1 = {p89, pab, pcd, pef};
                paf[tile * 2 + 0] = *(const bf16x8*)&f0;
                paf[tile * 2 + 1] = *(const bf16x8*)&f1;
            }
        }

        // ---- PV: O[q][dh], 2 dh-tiles x 8 k-frags over 128 kv ----
#pragma unroll
        for (int kf = 0; kf < 8; ++kf) {
            const bf16x8 v0 = *(const bf16x8*)&Vt[cur][swzV(r31, kf * 2 + hi)];
            acc0 = MFMA32(paf[kf], v0, acc0);
        }
#pragma unroll
        for (int kf = 0; kf < 8; ++kf) {
            const bf16x8 v1 = *(const bf16x8*)&Vt[cur][swzV(32 + r31, kf * 2 + hi)];
            acc1 = MFMA32(paf[kf], v1, acc1);
        }
    }

    // ---- epilogue: reduce lp across halves, redistribute, store ----
    const float lv = lp + __shfl_xor(lp, 32);
    const float inv = 1.0f / lv;      // for q = r31
#pragma unroll
    for (int reg = 0; reg < 16; ++reg) {
        const int qr = (reg & 3) + 8 * (reg >> 2) + 4 * hi;
        const float ir = __shfl(inv, qr);
        const int qs = q0 + qr;
        float* dst = &Aw[((size_t)b * Sn + qs) * Dn + h * DHn + r31];
        dst[0]  = acc0[reg] * ir;
        dst[32] = acc1[reg] * ir;
    }
}

// ---------------------------------------------------------------------------
// LayerNorm over D=1024 per (b,s) row; f32 output.
// ---------------------------------------------------------------------------
__global__ __launch_bounds__(256) void ln_kernel(
    const float* __restrict__ Aw, const float* __restrict__ gamma,
    const float* __restrict__ beta, float* __restrict__ out)
{
    const int row = blockIdx.x;
    const int tid = threadIdx.x;
    const int d0 = tid * 4;
    const float4 x = *(const float4*)&Aw[(size_t)row * Dn + d0];
    float sum = x.x + x.y + x.z + x.w;
    float sq = x.x * x.x + x.y * x.y + x.z * x.z + x.w * x.w;
    for (int off = 32; off; off >>= 1) {
        sum += __shfl_xor(sum, off);
        sq += __shfl_xor(sq, off);
    }
    __shared__ float red[8];
    const int lane = tid & 63, wave = tid >> 6;
    if (lane == 0) { red[wave] = sum; red[wave + 4] = sq; }
    __syncthreads();
    if (tid == 0) {
        red[0] = red[0] + red[1] + red[2] + red[3];
        red[4] = red[4] + red[5] + red[6] + red[7];
    }
    __syncthreads();
    sum = red[0]; sq = red[4];
    const float mu = sum * (1.0f / Dn);
    const float var = sq * (1.0f / Dn) - mu * mu;
    const float rs = rsqrtf(var + 1e-5f);

    const float4 gv = *(const float4*)&gamma[d0];
    const float4 bv = *(const float4*)&beta[d0];
    float4 ov;
    ov.x = (x.x - mu) * rs * gv.x + bv.x;
    ov.y = (x.y - mu) * rs * gv.y + bv.y;
    ov.z = (x.z - mu) * rs * gv.z + bv.z;
    ov.w = (x.w - mu) * rs * gv.w + bv.w;
    *(float4*)&out[(size_t)row * Dn + d0] = ov;
}

extern "C" void kernel_launch(void* const* d_in, const int* in_sizes, int n_in,
                              void* d_out, int out_size, void* d_ws, size_t ws_size,
                              hipStream_t stream)
{
    const float* x_qk = (const float*)d_in[0];
    const float* x_v  = (const float*)d_in[1];
    const float* W_qk = (const float*)d_in[2];
    const float* b_qk = (const float*)d_in[3];
    const float* W_v  = (const float*)d_in[4];
    const float* b_v  = (const float*)d_in[5];
    const float* g    = (const float*)d_in[6];
    const float* be   = (const float*)d_in[7];

    char* ws = (char*)d_ws;
    ushort* Qw    = (ushort*)(ws);                  //  8 MB bf16 (b,h,s,dh)
    ushort* Kw    = (ushort*)(ws + (8u  << 20));    //  8 MB bf16 (b,h,s,dh)
    ushort* Vtw   = (ushort*)(ws + (16u << 20));    //  8 MB bf16 (b,h,dh,s)
    float*  Aw    = (float*) (ws + (24u << 20));    // 16 MB f32  (b,s,D)
    ushort* xqkB  = (ushort*)(ws + (40u << 20));    //  8 MB bf16 [M][K]
    ushort* xvB   = (ushort*)(ws + (48u << 20));    //  8 MB bf16 [M][K]
    ushort* WqkT  = (ushort*)(ws + (56u << 20));    //  4 MB bf16 [2048][1024]
    ushort* WvT   = (ushort*)(ws + (60u << 20));    //  2 MB bf16 [1024][1024]
    float*  ctab  = (float*) (ws + (62u << 20));    // 256 KB
    float*  stab  = (float*) (ws + (62u << 20) + (256u << 10));

    // 1) fused prep: cvt x2 + transpose x2 + RoPE table
    prep<<<7424, 256, 0, stream>>>(x_qk, x_v, W_qk, W_v,
                                   xqkB, xvB, WqkT, WvT, ctab, stab);
    // 2) both projections in one dispatch (x<16: QK+RoPE, x>=16: V^T)
    gemm_fused_all<<<dim3(24, 32), 256, 0, stream>>>(
        xqkB, xvB, WqkT, WvT, b_qk, b_v, ctab, stab, Qw, Kw, Vtw);
    // 3) flash attention, KVBLK=128 (half the barriers of r15)
    attn_mfma<<<dim3(16, 32), 256, 0, stream>>>(Qw, Kw, Vtw, Aw);
    // 4) LayerNorm
    ln_kernel<<<Bn * Sn, 256, 0, stream>>>(Aw, g, be, (float*)d_out);
}

// Round 20
// 137.740 us; speedup vs baseline: 1.1896x; 1.1896x over previous
//
#include <hip/hip_runtime.h>
#include <hip/hip_bf16.h>

// B=2, S=2048, D=1024, H=16, DH=64. f32 in/out; bf16 intermediates for MFMA.
#define Bn 2
#define Sn 2048
#define Dn 1024
#define Hn 16
#define DHn 64
#define Kd 1024
#define Mn (Bn * Sn)
#define LN10K 9.210340371976184f

typedef __attribute__((ext_vector_type(8))) short bf16x8;   // MFMA A/B frag
typedef __attribute__((ext_vector_type(4))) float f32x4;    // 16x16 C/D frag
typedef __attribute__((ext_vector_type(16))) float f32x16;  // 32x32 C/D frag

static __device__ __forceinline__ ushort f2bf(float f) {
    uint u = __float_as_uint(f);
    u += 0x7fff + ((u >> 16) & 1);   // round-nearest-even
    return (ushort)(u >> 16);
}
// packed f32x2 -> bf16x2 (RNE), lo = a, hi = b
static __device__ __forceinline__ uint cvtpk(float a, float b) {
    uint r;
    asm("v_cvt_pk_bf16_f32 %0, %1, %2" : "=v"(r) : "v"(a), "v"(b));
    return r;
}
// swap a.hi32lanes <-> b.lo32lanes
static __device__ __forceinline__ void plswap(uint& a, uint& b) {
    asm volatile("v_permlane32_swap_b32 %0, %1" : "+v"(a), "+v"(b));
}

#define MFMA16(a, b, c) __builtin_amdgcn_mfma_f32_16x16x32_bf16((a), (b), (c), 0, 0, 0)
#define MFMA32(a, b, c) __builtin_amdgcn_mfma_f32_32x32x16_bf16((a), (b), (c), 0, 0, 0)

// async global->LDS, 16B per lane. LDS dest is wave-uniform base + lane*16.
static __device__ __forceinline__ void gload16(const ushort* g, ushort* l) {
    __builtin_amdgcn_global_load_lds(
        (const __attribute__((address_space(1))) void*)g,
        (__attribute__((address_space(3))) void*)l, 16, 0, 0);
}

// XOR swizzle for [rows][128B] LDS tiles (16B granules).
static __device__ __forceinline__ int swz(int row, int col16) {
    return row * 128 + (((col16) * 16) ^ ((row & 7) << 4));
}

// ---------------------------------------------------------------------------
// Fused prep: [0,2048) cvt x_qk; [2048,4096) cvt x_v; [4096,6144) transpose
// W_qk; [6144,7168) transpose W_v; [7168,7424) RoPE table.
// ---------------------------------------------------------------------------
__global__ __launch_bounds__(256) void prep(
    const float* __restrict__ x_qk, const float* __restrict__ x_v,
    const float* __restrict__ W_qk, const float* __restrict__ W_v,
    ushort* __restrict__ xqkB, ushort* __restrict__ xvB,
    ushort* __restrict__ WqkT, ushort* __restrict__ WvT,
    float* __restrict__ ct, float* __restrict__ st)
{
    __shared__ ushort tle[32][33];
    const int blk = blockIdx.x;
    const int tid = threadIdx.x;

    if (blk < 4096) {
        const float* in = (blk < 2048) ? x_qk : x_v;
        ushort* out = (blk < 2048) ? xqkB : xvB;
        const int lb = (blk < 2048) ? blk : blk - 2048;
        const size_t i = ((size_t)lb * 256 + tid) * 8;
        const float4 a = *(const float4*)(in + i);
        const float4 b = *(const float4*)(in + i + 4);
        *(ushort4*)(out + i) =
            make_ushort4(f2bf(a.x), f2bf(a.y), f2bf(a.z), f2bf(a.w));
        *(ushort4*)(out + i + 4) =
            make_ushort4(f2bf(b.x), f2bf(b.y), f2bf(b.z), f2bf(b.w));
    } else if (blk < 7168) {
        const bool isQK = blk < 6144;
        const int t = isQK ? blk - 4096 : blk - 6144;
        const int C = isQK ? 2048 : 1024;
        const float* in = isQK ? W_qk : W_v;
        ushort* out = isQK ? WqkT : WvT;
        const int n0 = (isQK ? (t & 63) : (t & 31)) * 32;
        const int k0 = (isQK ? (t >> 6) : (t >> 5)) * 32;
        const int x = tid & 31, y = tid >> 5;
#pragma unroll
        for (int i = 0; i < 4; ++i)
            tle[y + 8 * i][x] = f2bf(in[(size_t)(k0 + y + 8 * i) * C + n0 + x]);
        __syncthreads();
#pragma unroll
        for (int i = 0; i < 4; ++i)
            out[(size_t)(n0 + y + 8 * i) * Kd + k0 + x] = tle[x][y + 8 * i];
    } else {
        const int idx = (blk - 7168) * 256 + tid;
        const int s = idx >> 5, fe = idx & 31;
        const float f = expf(-LN10K * (float)fe / 32.0f);
        const float a = (float)s * f;
        ct[idx] = cosf(a);
        st[idx] = sinf(a);
    }
}

// ---------------------------------------------------------------------------
// Combined MFMA GEMM (m97-style): blocks x<16 QK-projection (RoPE epilogue
// -> Q,K); x>=16 V-projection (-> V^T). 128x128 tile, BK=64, global_load_lds
// w=16 with xor-source, swizzled read.
// ---------------------------------------------------------------------------
__global__ __launch_bounds__(256) void gemm_fused_all(
    const ushort* __restrict__ xqkB, const ushort* __restrict__ xvB,
    const ushort* __restrict__ WqkT, const ushort* __restrict__ WvT,
    const float* __restrict__ b_qk, const float* __restrict__ b_v,
    const float* __restrict__ ctab, const float* __restrict__ stab,
    ushort* __restrict__ Qw, ushort* __restrict__ Kw, ushort* __restrict__ Vtw)
{
    __shared__ ushort Asm[128 * 64];
    __shared__ ushort Bsm[128 * 64];

    const bool isQK = blockIdx.x < 16;
    const ushort* A  = isQK ? xqkB : xvB;
    const ushort* Bt = isQK ? WqkT : WvT;
    const float* bias = isQK ? b_qk : b_v;
    const int nbase = (isQK ? blockIdx.x : blockIdx.x - 16) * 128;
    const int mbase = blockIdx.y * 128;

    const int tid = threadIdx.x;
    const int lane = tid & 63, w = tid >> 6;
    const int g = lane >> 4, c = lane & 15;
    const int wm = (w >> 1) * 64, wn = (w & 1) * 64;

    f32x4 acc[4][4];
#pragma unroll
    for (int mf = 0; mf < 4; ++mf)
#pragma unroll
        for (int nf = 0; nf < 4; ++nf)
            acc[mf][nf] = (f32x4){0.f, 0.f, 0.f, 0.f};

    const int sbase = w * 64 + lane;

    for (int k0 = 0; k0 < Kd; k0 += 64) {
#pragma unroll
        for (int j = 0; j < 4; ++j) {
            const int i = j * 256 + sbase;
            const int row = i >> 3, c16 = i & 7;
            const int kc = (c16 ^ (row & 7)) * 8;
            gload16(A + (size_t)(mbase + row) * Kd + k0 + kc,
                    &Asm[(size_t)(j * 256 + w * 64) * 8]);
            gload16(Bt + (size_t)(nbase + row) * Kd + k0 + kc,
                    &Bsm[(size_t)(j * 256 + w * 64) * 8]);
        }
        __syncthreads();

#pragma unroll
        for (int ks = 0; ks < 2; ++ks) {
            bf16x8 af[4], bfr[4];
#pragma unroll
            for (int mf = 0; mf < 4; ++mf) {
                const int row = wm + mf * 16 + c;
                af[mf] = *(const bf16x8*)((const char*)Asm + swz(row, ks * 4 + g));
            }
#pragma unroll
            for (int nf = 0; nf < 4; ++nf) {
                const int row = wn + nf * 16 + c;
                bfr[nf] = *(const bf16x8*)((const char*)Bsm + swz(row, ks * 4 + g));
            }
#pragma unroll
            for (int mf = 0; mf < 4; ++mf)
#pragma unroll
                for (int nf = 0; nf < 4; ++nf)
                    acc[mf][nf] = MFMA16(af[mf], bfr[nf], acc[mf][nf]);
        }
        __syncthreads();
    }

#pragma unroll
    for (int nf = 0; nf < 4; ++nf) {
        const int col = nbase + wn + nf * 16 + c;
        const float bs = bias[col];
        if (isQK) {
            const int dh = col & 63, h = (col >> 6) & 15, isK = col >> 10;
            ushort* dst = isK ? Kw : Qw;
            // Q: fold 1/sqrt(64) * log2(e) so attention exps are exp2
            const float sc = isK ? 1.0f : 0.18033688011112042f;
            const float* cr = ctab + (dh & 31);
            const float* sr = stab + (dh & 31);
#pragma unroll
            for (int mf = 0; mf < 4; ++mf) {
#pragma unroll
                for (int r = 0; r < 4; ++r) {
                    const int row = mbase + wm + mf * 16 + g * 4 + r;
                    const int s = row & 2047, b = row >> 11;
                    const float v = acc[mf][nf][r] + bs;
                    const float p = __shfl_xor(v, 1);
                    const float cs = cr[s * 32], sn = sr[s * 32];
                    const float ov = (c & 1) ? v * cs + p * sn
                                             : v * cs - p * sn;
                    dst[(((size_t)(b * Hn + h)) * Sn + s) * DHn + dh] =
                        f2bf(ov * sc);
                }
            }
        } else {
            const int h = col >> 6, dh = col & 63;
#pragma unroll
            for (int mf = 0; mf < 4; ++mf) {
#pragma unroll
                for (int r = 0; r < 4; ++r) {
                    const int row = mbase + wm + mf * 16 + g * 4 + r;
                    const int s = row & 2047, b = row >> 11;
                    const float v = acc[mf][nf][r] + bs;
                    Vtw[(((size_t)(b * Hn + h)) * DHn + dh) * Sn + s] = f2bf(v);
                }
            }
        }
    }
}

// ---------------------------------------------------------------------------
// MFMA flash attention (round 11 structure — best measured: 80.3 us).
// 32x32 frags, swapped QK^T, permlane P-rebuild, exp2 domain, counted-vmcnt
// triple-buffered pipeline: stage(t+2) after compute(t); per-iter sync is
// s_waitcnt vmcnt(4) + raw s_barrier.
// ---------------------------------------------------------------------------
__global__ __launch_bounds__(256) void attn_mfma(
    const ushort* __restrict__ Qg, const ushort* __restrict__ Kg,
    const ushort* __restrict__ Vtg, float* __restrict__ Aw)
{
    __shared__ char Kt[3][8192];   // [64 kv][64 d] bf16, swizzled
    __shared__ char Vt[3][8192];   // [64 dh][64 kv] bf16, swizzled

    const int tid = threadIdx.x;
    const int lane = tid & 63, w = tid >> 6;
    const int r31 = lane & 31, hi = lane >> 5;
    const int bh = blockIdx.y;
    const int b = bh >> 4, h = bh & 15;
    const int q0 = blockIdx.x * 128 + w * 32;

    // Q B-frags: lane holds Q[q0 + r31][kt*16 + hi*8 + j]
    const ushort* qp = Qg + ((size_t)bh * Sn + q0 + r31) * DHn + hi * 8;
    bf16x8 qf[4];
#pragma unroll
    for (int kt = 0; kt < 4; ++kt)
        qf[kt] = *(const bf16x8*)(qp + kt * 16);

    const ushort* Kb = Kg + (size_t)bh * Sn * DHn;
    const ushort* Vb = Vtg + (size_t)bh * DHn * Sn;

    // stage one 64x64 K tile + one 64x64 V^T tile: 4 gload16 per thread.
    auto stage = [&](int buf, int kb) {
#pragma unroll
        for (int j = 0; j < 2; ++j) {
            const int i = j * 256 + w * 64 + lane;
            const int row = i >> 3, c16 = i & 7;
            const int kc = (c16 ^ (row & 7)) * 8;
            gload16(Kb + (size_t)(kb + row) * DHn + kc,
                    (ushort*)&Kt[buf][(j * 256 + w * 64) * 16]);
            gload16(Vb + (size_t)row * Sn + kb + kc,
                    (ushort*)&Vt[buf][(j * 256 + w * 64) * 16]);
        }
    };

    // prologue: tiles 0 and 1 in flight (8 vmcnt ops/wave outstanding)
    stage(0, 0);
    stage(1, 64);

    f32x16 acc0, acc1;
#pragma unroll
    for (int i = 0; i < 16; ++i) { acc0[i] = 0.f; acc1[i] = 0.f; }
    float m = -1e30f, lp = 0.f;

    const int NT = Sn / 64;   // 32
    for (int t = 0; t < NT; ++t) {
        const int cur = t % 3;

        // ---- wait for buf[cur]'s 4 DMAs (keep the next tile's 4 in flight) --
        if (t < NT - 1) {
            asm volatile("s_waitcnt vmcnt(4)" ::: "memory");
        } else {
            asm volatile("s_waitcnt vmcnt(0)" ::: "memory");
        }
        __builtin_amdgcn_sched_barrier(0);
        __builtin_amdgcn_s_barrier();     // all waves' buf[cur] complete
        __builtin_amdgcn_sched_barrier(0);

        // ---- QK^T swapped: C[kv][q] for two 32-kv tiles ----
        f32x16 C0, C1;
#pragma unroll
        for (int i = 0; i < 16; ++i) { C0[i] = 0.f; C1[i] = 0.f; }
        __builtin_amdgcn_s_setprio(1);
#pragma unroll
        for (int kt = 0; kt < 4; ++kt) {
            const bf16x8 ka = *(const bf16x8*)&Kt[cur][swz(r31, kt * 2 + hi)];
            C0 = MFMA32(ka, qf[kt], C0);
        }
#pragma unroll
        for (int kt = 0; kt < 4; ++kt) {
            const bf16x8 ka = *(const bf16x8*)&Kt[cur][swz(32 + r31, kt * 2 + hi)];
            C1 = MFMA32(ka, qf[kt], C1);
        }
        __builtin_amdgcn_s_setprio(0);

        // ---- row max (q = r31): in-reg tree + partner half ----
        float mx[8];
#pragma unroll
        for (int i = 0; i < 8; ++i)
            mx[i] = fmaxf(fmaxf(C0[i], C0[i + 8]), fmaxf(C1[i], C1[i + 8]));
        mx[0] = fmaxf(mx[0], mx[4]); mx[1] = fmaxf(mx[1], mx[5]);
        mx[2] = fmaxf(mx[2], mx[6]); mx[3] = fmaxf(mx[3], mx[7]);
        float pmax = fmaxf(fmaxf(mx[0], mx[1]), fmaxf(mx[2], mx[3]));
        pmax = fmaxf(pmax, __shfl_xor(pmax, 32));

        // ---- defer-max rescale (rare; threshold 8*log2e) ----
        if (__any(pmax > m + 11.5f)) {
            const float mn = fmaxf(m, pmax);
            const float a = exp2f(m - mn);
            m = mn;
            lp *= a;
#pragma unroll
            for (int reg = 0; reg < 16; ++reg) {
                const int qr = (reg & 3) + 8 * (reg >> 2) + 4 * hi;
                const float ar = __shfl(a, qr);
                acc0[reg] *= ar;
                acc1[reg] *= ar;
            }
        }

        // ---- exp2 + pack + permlane -> PV A-frags ----
        bf16x8 paf[4];
#pragma unroll
        for (int tile = 0; tile < 2; ++tile) {
            const f32x16& C = tile ? C1 : C0;
            float e[16];
#pragma unroll
            for (int i = 0; i < 16; ++i) e[i] = exp2f(C[i] - m);
            float s = 0.f;
#pragma unroll
            for (int i = 0; i < 16; ++i) s += e[i];
            lp += s;
            uint p01 = cvtpk(e[0], e[1]),  p23 = cvtpk(e[2], e[3]);
            uint p45 = cvtpk(e[4], e[5]),  p67 = cvtpk(e[6], e[7]);
            uint p89 = cvtpk(e[8], e[9]),  pab = cvtpk(e[10], e[11]);
            uint pcd = cvtpk(e[12], e[13]), pef = cvtpk(e[14], e[15]);
            plswap(p01, p45); plswap(p23, p67);   // kt0: kv 0-15
            plswap(p89, pcd); plswap(pab, pef);   // kt1: kv 16-31
            uint4 f0 = {p01, p23, p45, p67};
            uint4 f1 = {p89, pab, pcd, pef};
            paf[tile * 2 + 0] = *(const bf16x8*)&f0;
            paf[tile * 2 + 1] = *(const bf16x8*)&f1;
        }

        // ---- PV: O[q][dh], 2 dh-tiles x 4 k-frags ----
        __builtin_amdgcn_s_setprio(1);
#pragma unroll
        for (int kf = 0; kf < 4; ++kf) {
            const bf16x8 v0 = *(const bf16x8*)&Vt[cur][swz(r31, kf * 2 + hi)];
            acc0 = MFMA32(paf[kf], v0, acc0);
        }
#pragma unroll
        for (int kf = 0; kf < 4; ++kf) {
            const bf16x8 v1 = *(const bf16x8*)&Vt[cur][swz(32 + r31, kf * 2 + hi)];
            acc1 = MFMA32(paf[kf], v1, acc1);
        }
        __builtin_amdgcn_s_setprio(0);

        // ---- issue stage for tile t+2 (buffer safe: its last readers were
        //      iter t-1, and barrier-t proved they're done) ----
        __builtin_amdgcn_sched_barrier(0);
        if (t + 2 < NT) stage((t + 2) % 3, (t + 2) * 64);
    }

    // ---- epilogue: reduce lp across halves, redistribute, store ----
    const float lv = lp + __shfl_xor(lp, 32);
    const float inv = 1.0f / lv;      // for q = r31
#pragma unroll
    for (int reg = 0; reg < 16; ++reg) {
        const int qr = (reg & 3) + 8 * (reg >> 2) + 4 * hi;
        const float ir = __shfl(inv, qr);
        const int qs = q0 + qr;
        float* dst = &Aw[((size_t)b * Sn + qs) * Dn + h * DHn + r31];
        dst[0]  = acc0[reg] * ir;
        dst[32] = acc1[reg] * ir;
    }
}

// ---------------------------------------------------------------------------
// LayerNorm over D=1024 per (b,s) row; f32 output.
// ---------------------------------------------------------------------------
__global__ __launch_bounds__(256) void ln_kernel(
    const float* __restrict__ Aw, const float* __restrict__ gamma,
    const float* __restrict__ beta, float* __restrict__ out)
{
    const int row = blockIdx.x;
    const int tid = threadIdx.x;
    const int d0 = tid * 4;
    const float4 x = *(const float4*)&Aw[(size_t)row * Dn + d0];
    float sum = x.x + x.y + x.z + x.w;
    float sq = x.x * x.x + x.y * x.y + x.z * x.z + x.w * x.w;
    for (int off = 32; off; off >>= 1) {
        sum += __shfl_xor(sum, off);
        sq += __shfl_xor(sq, off);
    }
    __shared__ float red[8];
    const int lane = tid & 63, wave = tid >> 6;
    if (lane == 0) { red[wave] = sum; red[wave + 4] = sq; }
    __syncthreads();
    if (tid == 0) {
        red[0] = red[0] + red[1] + red[2] + red[3];
        red[4] = red[4] + red[5] + red[6] + red[7];
    }
    __syncthreads();
    sum = red[0]; sq = red[4];
    const float mu = sum * (1.0f / Dn);
    const float var = sq * (1.0f / Dn) - mu * mu;
    const float rs = rsqrtf(var + 1e-5f);

    const float4 gv = *(const float4*)&gamma[d0];
    const float4 bv = *(const float4*)&beta[d0];
    float4 ov;
    ov.x = (x.x - mu) * rs * gv.x + bv.x;
    ov.y = (x.y - mu) * rs * gv.y + bv.y;
    ov.z = (x.z - mu) * rs * gv.z + bv.z;
    ov.w = (x.w - mu) * rs * gv.w + bv.w;
    *(float4*)&out[(size_t)row * Dn + d0] = ov;
}

extern "C" void kernel_launch(void* const* d_in, const int* in_sizes, int n_in,
                              void* d_out, int out_size, void* d_ws, size_t ws_size,
                              hipStream_t stream)
{
    const float* x_qk = (const float*)d_in[0];
    const float* x_v  = (const float*)d_in[1];
    const float* W_qk = (const float*)d_in[2];
    const float* b_qk = (const float*)d_in[3];
    const float* W_v  = (const float*)d_in[4];
    const float* b_v  = (const float*)d_in[5];
    const float* g    = (const float*)d_in[6];
    const float* be   = (const float*)d_in[7];

    char* ws = (char*)d_ws;
    ushort* Qw    = (ushort*)(ws);                  //  8 MB bf16 (b,h,s,dh)
    ushort* Kw    = (ushort*)(ws + (8u  << 20));    //  8 MB bf16 (b,h,s,dh)
    ushort* Vtw   = (ushort*)(ws + (16u << 20));    //  8 MB bf16 (b,h,dh,s)
    float*  Aw    = (float*) (ws + (24u << 20));    // 16 MB f32  (b,s,D)
    ushort* xqkB  = (ushort*)(ws + (40u << 20));    //  8 MB bf16 [M][K]
    ushort* xvB   = (ushort*)(ws + (48u << 20));    //  8 MB bf16 [M][K]
    ushort* WqkT  = (ushort*)(ws + (56u << 20));    //  4 MB bf16 [2048][1024]
    ushort* WvT   = (ushort*)(ws + (60u << 20));    //  2 MB bf16 [1024][1024]
    float*  ctab  = (float*) (ws + (62u << 20));    // 256 KB
    float*  stab  = (float*) (ws + (62u << 20) + (256u << 10));

    // 1) fused prep: cvt x2 + transpose x2 + RoPE table
    prep<<<7424, 256, 0, stream>>>(x_qk, x_v, W_qk, W_v,
                                   xqkB, xvB, WqkT, WvT, ctab, stab);
    // 2) both projections in one dispatch (x<16: QK+RoPE, x>=16: V^T)
    gemm_fused_all<<<dim3(24, 32), 256, 0, stream>>>(
        xqkB, xvB, WqkT, WvT, b_qk, b_v, ctab, stab, Qw, Kw, Vtw);
    // 3) flash attention (round-11 structure)
    attn_mfma<<<dim3(16, 32), 256, 0, stream>>>(Qw, Kw, Vtw, Aw);
    // 4) LayerNorm
    ln_kernel<<<Bn * Sn, 256, 0, stream>>>(Aw, g, be, (float*)d_out);
}